// Round 3
// baseline (177.975 us; speedup 1.0000x reference)
//
#include <hip/hip_runtime.h>

#define DMODEL 768
#define NHEAD  12
#define DK     64
#define NB     2
#define SEQ    2048
#define NTOK   (NB*SEQ)     // 4096
#define GKIT   (DMODEL/32)  // 24

using bf16x8 = __attribute__((ext_vector_type(8))) short;
using f32x4  = __attribute__((ext_vector_type(4))) float;

typedef __attribute__((address_space(1))) const unsigned int gas_u32;
typedef __attribute__((address_space(3))) unsigned int las_u32;

__device__ __forceinline__ void gload_lds16(const void* g, void* l) {
  __builtin_amdgcn_global_load_lds((gas_u32*)g, (las_u32*)l, 16, 0, 0);
}

__device__ __forceinline__ unsigned short f2bf(float f) {
  unsigned int u = __builtin_bit_cast(unsigned int, f);
  u = (u + 0x7FFFu + ((u >> 16) & 1u)) >> 16;
  return (unsigned short)u;
}

__device__ __forceinline__ unsigned cvtpk_bf16(float lo, float hi) {
  unsigned r;
  asm volatile("v_cvt_pk_bf16_f32 %0, %1, %2" : "=v"(r) : "v"(lo), "v"(hi));
  return r;
}

// ---------------- W (f32, [K][N]) -> W^T (bf16, [N][K]) + mask bias ----------------
__global__ __launch_bounds__(256) void wtrans_kernel(
    const float* __restrict__ w0, const float* __restrict__ w1,
    const float* __restrict__ w2, const float* __restrict__ w3,
    unsigned short* __restrict__ o0, unsigned short* __restrict__ o1,
    unsigned short* __restrict__ o2, unsigned short* __restrict__ o3,
    const int* __restrict__ mask, float* __restrict__ maskbias) {
  __shared__ unsigned short tile[64][80];
  int z = blockIdx.z;
  if (z == 4) {
    if (blockIdx.x == 0 && blockIdx.y == 0) {
      for (int i = threadIdx.x; i < NB * SEQ; i += 256)
        maskbias[i] = mask[i] ? 0.f : -1.4426950408889634e9f;  // -1e9 * log2(e)
    }
    return;
  }
  const float* in = z == 0 ? w0 : z == 1 ? w1 : z == 2 ? w2 : w3;
  unsigned short* out = z == 0 ? o0 : z == 1 ? o1 : z == 2 ? o2 : o3;
  int c0 = blockIdx.x * 64, r0 = blockIdx.y * 64;
  int t = threadIdx.x, row = t >> 2, ch = t & 3;
#pragma unroll
  for (int j4 = 0; j4 < 4; ++j4) {
    float4 f = *(const float4*)(in + (size_t)(r0 + row) * DMODEL + c0 + ch * 16 + j4 * 4);
    tile[row][ch * 16 + j4 * 4 + 0] = f2bf(f.x);
    tile[row][ch * 16 + j4 * 4 + 1] = f2bf(f.y);
    tile[row][ch * 16 + j4 * 4 + 2] = f2bf(f.z);
    tile[row][ch * 16 + j4 * 4 + 3] = f2bf(f.w);
  }
  __syncthreads();
  uint4 wA, wB;
  unsigned short* ta = (unsigned short*)&wA;
  unsigned short* tb = (unsigned short*)&wB;
#pragma unroll
  for (int j = 0; j < 8; ++j) { ta[j] = tile[ch * 16 + j][row]; tb[j] = tile[ch * 16 + 8 + j][row]; }
  unsigned short* ob = out + (size_t)(c0 + row) * DMODEL + r0 + ch * 16;
  *(uint4*)ob = wA;
  *(uint4*)(ob + 8) = wB;
}

// ---------------- GEMM core: 128x128 tile, BK=32, dbuf; A either f32 or bf16 ----------------
template<bool AF32>
__device__ __forceinline__ void gemm_core(const void* Ap, const unsigned short* BT,
    char* gsm, int rowbase, int colbase, f32x4 acc[4][4]) {
  unsigned short* AsAll = (unsigned short*)gsm;            // [2][4096]
  unsigned short* BsAll = (unsigned short*)(gsm + 16384);  // [2][4096]
  int t = threadIdx.x, lane = t & 63, wave = t >> 6;
  int wr = wave >> 1, wc = wave & 1, l16 = lane & 15, lk = lane >> 4;
  int r16 = lane >> 2, c4 = lane & 3;

  auto stage = [&](int kt, int buf) {
    unsigned short* As = AsAll + buf * 4096;
    unsigned short* Bs = BsAll + buf * 4096;
#pragma unroll
    for (int iss = 0; iss < 2; ++iss) {
      int rb = wave * 32 + iss * 16;
      int row = rb + r16;
      if (AF32) {
        const float* ap = (const float*)Ap + (size_t)(rowbase + row) * DMODEL + kt * 32 + c4 * 8;
        float4 f0 = *(const float4*)ap;
        float4 f1 = *(const float4*)(ap + 4);
        uint4 w;
        w.x = cvtpk_bf16(f0.x, f0.y); w.y = cvtpk_bf16(f0.z, f0.w);
        w.z = cvtpk_bf16(f1.x, f1.y); w.w = cvtpk_bf16(f1.z, f1.w);
        *(uint4*)(As + row * 32 + c4 * 8) = w;
      } else {
        gload_lds16((const unsigned short*)Ap + (size_t)(rowbase + row) * DMODEL + kt * 32 + c4 * 8,
                    As + rb * 32);
      }
      gload_lds16(BT + (size_t)(colbase + row) * DMODEL + kt * 32 + c4 * 8, Bs + rb * 32);
    }
  };

  stage(0, 0);
  __syncthreads();
  for (int kt = 0; kt < GKIT; ++kt) {
    int cur = kt & 1;
    if (kt < GKIT - 1) stage(kt + 1, cur ^ 1);
    unsigned short* As = AsAll + cur * 4096;
    unsigned short* Bs = BsAll + cur * 4096;
    bf16x8 a[4], bb[4];
#pragma unroll
    for (int m = 0; m < 4; ++m) a[m] = *(const bf16x8*)(As + (wr * 64 + m * 16 + l16) * 32 + lk * 8);
#pragma unroll
    for (int n = 0; n < 4; ++n) bb[n] = *(const bf16x8*)(Bs + (wc * 64 + n * 16 + l16) * 32 + lk * 8);
    __builtin_amdgcn_s_setprio(1);
#pragma unroll
    for (int m = 0; m < 4; ++m)
#pragma unroll
      for (int n = 0; n < 4; ++n)
        acc[m][n] = __builtin_amdgcn_mfma_f32_16x16x32_bf16(a[m], bb[n], acc[m][n], 0, 0, 0);
    __builtin_amdgcn_s_setprio(0);
    __syncthreads();
  }
}

struct QKVArgs {
  const float* A[3];
  const unsigned short* BT[3];
  const float* bias[3];
  unsigned short* out[3];   // Qh, Kh, Vt(transposed)
  float scale;              // for z==0 (Q): 0.125*log2(e)
};

// QKV projections from f32 inputs; z=2 writes V transposed [B,H,DK,S]
__global__ __launch_bounds__(256) void gemm_qkv_kernel(QKVArgs ga) {
  __shared__ char gsm[32768];
  int z = blockIdx.z;
  int rowbase = blockIdx.x * 128, colbase = blockIdx.y * 128;
  f32x4 acc[4][4];
#pragma unroll
  for (int m = 0; m < 4; ++m)
#pragma unroll
    for (int n = 0; n < 4; ++n) acc[m][n] = (f32x4){0.f, 0.f, 0.f, 0.f};
  gemm_core<true>(ga.A[z], ga.BT[z], gsm, rowbase, colbase, acc);
  const float* bias = ga.bias[z];
  int t = threadIdx.x, lane = t & 63, wave = t >> 6;
  int wr = wave >> 1, wc = wave & 1, l16 = lane & 15, lk = lane >> 4;
  if (z == 2) {
    // transpose epilogue: acc -> LDS (swizzled) -> coalesced Vt writes
#pragma unroll
    for (int n = 0; n < 4; ++n) {
      int c = wc * 64 + n * 16 + l16;
      float bv = bias[colbase + c];
      int swz = (c & 7) << 4;
#pragma unroll
      for (int m = 0; m < 4; ++m) {
        uint2 w;
        w.x = cvtpk_bf16(acc[m][n][0] + bv, acc[m][n][1] + bv);
        w.y = cvtpk_bf16(acc[m][n][2] + bv, acc[m][n][3] + bv);
        int rp = wr * 64 + m * 16 + lk * 4;
        *(uint2*)(gsm + c * 256 + ((rp * 2) ^ swz)) = w;
      }
    }
    __syncthreads();
    int c = t >> 1, hf = t & 1;
    int swz2 = (c & 7) << 4;
    int gcol = colbase + c;
    int hh = gcol >> 6, dd = gcol & 63;
    int bb2 = rowbase >> 11;
    int s0 = (rowbase & 2047) + hf * 64;
    unsigned short* dst = ga.out[2] + ((size_t)(bb2 * NHEAD + hh) * DK + dd) * SEQ + s0;
#pragma unroll
    for (int j = 0; j < 8; ++j) {
      uint4 w = *(const uint4*)(gsm + c * 256 + ((hf * 128 + j * 16) ^ swz2));
      *(uint4*)(dst + j * 8) = w;
    }
  } else {
    float scale = (z == 0) ? ga.scale : 1.f;
    unsigned short* out = ga.out[z];
#pragma unroll
    for (int n = 0; n < 4; ++n) {
      int gcol = colbase + wc * 64 + n * 16 + l16;
      float bv = bias[gcol];
      int h = gcol >> 6, d = gcol & 63;
#pragma unroll
      for (int m = 0; m < 4; ++m) {
        int growb = rowbase + wr * 64 + m * 16 + lk * 4;
#pragma unroll
        for (int i = 0; i < 4; ++i) {
          int grow = growb + i;
          int b = grow >> 11, s = grow & 2047;
          out[((size_t)(b * NHEAD + h) * SEQ + s) * DK + d] = f2bf((acc[m][n][i] + bv) * scale);
        }
      }
    }
  }
}

// Output projection: out = AO @ Wo + bo, f32 result
__global__ __launch_bounds__(256) void gemm_o_kernel(
    const unsigned short* __restrict__ A, const unsigned short* __restrict__ BT,
    const float* __restrict__ bias, float* __restrict__ out) {
  __shared__ char gsm[32768];
  int rowbase = blockIdx.x * 128, colbase = blockIdx.y * 128;
  f32x4 acc[4][4];
#pragma unroll
  for (int m = 0; m < 4; ++m)
#pragma unroll
    for (int n = 0; n < 4; ++n) acc[m][n] = (f32x4){0.f, 0.f, 0.f, 0.f};
  gemm_core<false>(A, BT, gsm, rowbase, colbase, acc);
  int lane = threadIdx.x & 63, wave = threadIdx.x >> 6;
  int wr = wave >> 1, wc = wave & 1, l16 = lane & 15, lk = lane >> 4;
#pragma unroll
  for (int n = 0; n < 4; ++n) {
    int gcol = colbase + wc * 64 + n * 16 + l16;
    float bv = bias[gcol];
#pragma unroll
    for (int m = 0; m < 4; ++m) {
      int growb = rowbase + wr * 64 + m * 16 + lk * 4;
#pragma unroll
      for (int i = 0; i < 4; ++i)
        out[(size_t)(growb + i) * DMODEL + gcol] = acc[m][n][i] + bv;
    }
  }
}

// ---------------- flash attention: 8 waves, in-block KV split, T14 single-buffer ----------------
__global__ __launch_bounds__(512, 6) void flash_kernel(
    const unsigned short* __restrict__ Qh, const unsigned short* __restrict__ Kh,
    const unsigned short* __restrict__ Vt, const float* __restrict__ maskbias,
    unsigned short* __restrict__ AO) {
  __shared__ char smem[49152];
  // [0,16384): Ks 2 groups x [64 keys][64 dk] bf16 (chunk-swizzled)
  // [16384,32768): Vs 2 groups x [64 d][64 keys]
  // [32768,49152): Ps 8 waves x [16 q][64 keys]

  int orig = blockIdx.x;
  int xcd = orig & 7, idx = orig >> 3;     // 96 blocks per XCD chunk
  int bh = xcd * 3 + (idx >> 5);
  int qt = idx & 31;
  int b = bh / NHEAD, h = bh % NHEAD;

  int t = threadIdx.x, lane = t & 63, wave = t >> 6;
  int g = wave >> 2, wq = wave & 3;
  int l16 = lane & 15, lk = lane >> 4;
  int wgt = t & 255;
  int KB0 = g * 1024;

  size_t headQ = (size_t)bh * SEQ * DK;
  size_t headV = (size_t)bh * DK * SEQ;
  int qbase = qt * 64 + wq * 16;

  const unsigned short* Kg = Kh + headQ + (size_t)KB0 * DK;
  const unsigned short* Vg = Vt + headV + KB0;
  const float* mb = maskbias + b * SEQ + KB0;

  char* KsB = smem + g * 8192;
  char* VsB = smem + 16384 + g * 8192;
  char* Pw  = smem + 32768 + wave * 2048;

  bf16x8 aq0 = *(const bf16x8*)(Qh + headQ + (size_t)(qbase + l16) * DK + lk * 8);
  bf16x8 aq1 = *(const bf16x8*)(Qh + headQ + (size_t)(qbase + l16) * DK + 32 + lk * 8);

  // staging geometry: 256 lanes/group cover 64 rows x 4 chunk-pairs
  int sr = wgt >> 2, sc = wgt & 3;
  int koff = sr * DK + sc * 16;            // elements
  int voff = sr * SEQ + sc * 16;           // elements
  int db0 = sr * 128 + (((sc * 2) ^ (sr & 7)) << 4);
  int db1 = sr * 128 + (((sc * 2 + 1) ^ (sr & 7)) << 4);

  uint4 kr0, kr1, vr0, vr1;
  kr0 = *(const uint4*)(Kg + koff);
  kr1 = *(const uint4*)(Kg + koff + 8);
  vr0 = *(const uint4*)(Vg + voff);
  vr1 = *(const uint4*)(Vg + voff + 8);
  *(uint4*)(KsB + db0) = kr0; *(uint4*)(KsB + db1) = kr1;
  *(uint4*)(VsB + db0) = vr0; *(uint4*)(VsB + db1) = vr1;
  __syncthreads();

  float m_i = -1e30f, l_i = 0.f;
  f32x4 o[4];
#pragma unroll
  for (int n = 0; n < 4; ++n) o[n] = (f32x4){0.f, 0.f, 0.f, 0.f};

  for (int kt = 0; kt < 16; ++kt) {
    if (kt < 15) {  // T14: issue next tile's loads early (regs)
      kr0 = *(const uint4*)(Kg + koff + (kt + 1) * 4096);
      kr1 = *(const uint4*)(Kg + koff + (kt + 1) * 4096 + 8);
      vr0 = *(const uint4*)(Vg + voff + (kt + 1) * 64);
      vr1 = *(const uint4*)(Vg + voff + (kt + 1) * 64 + 8);
    }

    // QK^T (swapped): rows = keys, cols = q; maskbias as C-in
    f32x4 sv[4];
    __builtin_amdgcn_s_setprio(1);
#pragma unroll
    for (int n = 0; n < 4; ++n) {
      f32x4 bias = *(const f32x4*)(mb + kt * 64 + n * 16 + lk * 4);
      int key = n * 16 + l16;
      bf16x8 k0 = *(const bf16x8*)(KsB + ((key * 128 + lk * 16) ^ ((key & 7) << 4)));
      bf16x8 k1 = *(const bf16x8*)(KsB + ((key * 128 + 64 + lk * 16) ^ ((key & 7) << 4)));
      f32x4 zz = __builtin_amdgcn_mfma_f32_16x16x32_bf16(k1, aq1, bias, 0, 0, 0);
      sv[n] = __builtin_amdgcn_mfma_f32_16x16x32_bf16(k0, aq0, zz, 0, 0, 0);
    }
    __builtin_amdgcn_s_setprio(0);

    float pmax = -3.0e38f;
#pragma unroll
    for (int n = 0; n < 4; ++n)
#pragma unroll
      for (int i = 0; i < 4; ++i) pmax = fmaxf(pmax, sv[n][i]);
    pmax = fmaxf(pmax, __shfl_xor(pmax, 16));
    pmax = fmaxf(pmax, __shfl_xor(pmax, 32));

    if (__any(pmax > m_i + 8.0f)) {  // defer-max (log2 domain)
      float mnew = fmaxf(m_i, pmax);
      float corr = exp2f(m_i - mnew);
      l_i *= corr; m_i = mnew;
      float c0 = __shfl(corr, lk * 4 + 0);
      float c1 = __shfl(corr, lk * 4 + 1);
      float c2 = __shfl(corr, lk * 4 + 2);
      float c3 = __shfl(corr, lk * 4 + 3);
#pragma unroll
      for (int t4 = 0; t4 < 4; ++t4) {
        o[t4][0] *= c0; o[t4][1] *= c1; o[t4][2] *= c2; o[t4][3] *= c3;
      }
    }

    float su = 0.f;
#pragma unroll
    for (int n = 0; n < 4; ++n)
#pragma unroll
      for (int i = 0; i < 4; ++i) { sv[n][i] = exp2f(sv[n][i] - m_i); su += sv[n][i]; }
    su += __shfl_xor(su, 16);
    su += __shfl_xor(su, 32);
    l_i += su;

    // P -> wave-private LDS (swizzled), then A-fragments
#pragma unroll
    for (int n = 0; n < 4; ++n) {
      uint2 w;
      w.x = cvtpk_bf16(sv[n][0], sv[n][1]);
      w.y = cvtpk_bf16(sv[n][2], sv[n][3]);
      int byt = (l16 * 128 + n * 32 + lk * 8) ^ ((l16 & 7) << 4);
      *(uint2*)(Pw + byt) = w;
    }
    bf16x8 ap0 = *(const bf16x8*)(Pw + ((l16 * 128 + lk * 16) ^ ((l16 & 7) << 4)));
    bf16x8 ap1 = *(const bf16x8*)(Pw + ((l16 * 128 + 64 + lk * 16) ^ ((l16 & 7) << 4)));

    __builtin_amdgcn_s_setprio(1);
#pragma unroll
    for (int t4 = 0; t4 < 4; ++t4) {
      int d = t4 * 16 + l16;
      bf16x8 bv0 = *(const bf16x8*)(VsB + ((d * 128 + lk * 16) ^ ((d & 7) << 4)));
      bf16x8 bv1 = *(const bf16x8*)(VsB + ((d * 128 + 64 + lk * 16) ^ ((d & 7) << 4)));
      o[t4] = __builtin_amdgcn_mfma_f32_16x16x32_bf16(ap0, bv0, o[t4], 0, 0, 0);
      o[t4] = __builtin_amdgcn_mfma_f32_16x16x32_bf16(ap1, bv1, o[t4], 0, 0, 0);
    }
    __builtin_amdgcn_s_setprio(0);

    __syncthreads();                  // everyone done reading tile kt
    if (kt < 15) {                    // commit tile kt+1
      *(uint4*)(KsB + db0) = kr0; *(uint4*)(KsB + db1) = kr1;
      *(uint4*)(VsB + db0) = vr0; *(uint4*)(VsB + db1) = vr1;
    }
    __syncthreads();                  // writes visible
  }

  // merge the two KV-split halves (group 1 publishes, group 0 combines+writes)
  float* osc = (float*)smem;                     // [64][68] f32
  float* mls = (float*)(smem + 64 * 68 * 4);     // [64][2]
  if (g == 1) {
#pragma unroll
    for (int t4 = 0; t4 < 4; ++t4)
#pragma unroll
      for (int i = 0; i < 4; ++i)
        osc[(wq * 16 + lk * 4 + i) * 68 + t4 * 16 + l16] = o[t4][i];
    if (lk == 0) {
      mls[(wq * 16 + l16) * 2] = m_i;
      mls[(wq * 16 + l16) * 2 + 1] = l_i;
    }
  }
  __syncthreads();
  if (g == 0) {
    int qq = wq * 16 + l16;
    float mB = mls[qq * 2], lB = mls[qq * 2 + 1];
    float mst = fmaxf(m_i, mB);
    float fa = exp2f(m_i - mst), fb = exp2f(mB - mst);
    float linv = 1.f / (l_i * fa + lB * fb);
    float a_r[4], b_r[4], li_r[4];
#pragma unroll
    for (int i = 0; i < 4; ++i) {
      int src = lk * 4 + i;
      a_r[i] = __shfl(fa, src); b_r[i] = __shfl(fb, src); li_r[i] = __shfl(linv, src);
    }
#pragma unroll
    for (int t4 = 0; t4 < 4; ++t4) {
      int col = h * DK + t4 * 16 + l16;
#pragma unroll
      for (int i = 0; i < 4; ++i) {
        int q = wq * 16 + lk * 4 + i;
        float oB = osc[q * 68 + t4 * 16 + l16];
        float val = (o[t4][i] * a_r[i] + oB * b_r[i]) * li_r[i];
        AO[(size_t)(b * SEQ + qt * 64 + q) * DMODEL + col] = f2bf(val);
      }
    }
  }
}

extern "C" void kernel_launch(void* const* d_in, const int* in_sizes, int n_in,
                              void* d_out, int out_size, void* d_ws, size_t ws_size,
                              hipStream_t stream) {
  const float* gq  = (const float*)d_in[0];
  const float* gk  = (const float*)d_in[1];
  const float* gv  = (const float*)d_in[2];
  const int* gmask = (const int*)d_in[3];
  const float* gWq = (const float*)d_in[4];
  const float* gbq = (const float*)d_in[5];
  const float* gWk = (const float*)d_in[6];
  const float* gbk = (const float*)d_in[7];
  const float* gWv = (const float*)d_in[8];
  const float* gbv = (const float*)d_in[9];
  const float* gWo = (const float*)d_in[10];
  const float* gbo = (const float*)d_in[11];
  float* out = (float*)d_out;

  char* ws = (char*)d_ws;
  const size_t XSZ = (size_t)NTOK * DMODEL * 2;
  const size_t WSZ = (size_t)DMODEL * DMODEL * 2;
  unsigned short* WqT = (unsigned short*)ws; ws += WSZ;
  unsigned short* WkT = (unsigned short*)ws; ws += WSZ;
  unsigned short* WvT = (unsigned short*)ws; ws += WSZ;
  unsigned short* WoT = (unsigned short*)ws; ws += WSZ;
  unsigned short* Qh  = (unsigned short*)ws; ws += XSZ;
  unsigned short* Kh  = (unsigned short*)ws; ws += XSZ;
  unsigned short* Vt  = (unsigned short*)ws; ws += XSZ;
  unsigned short* AO  = (unsigned short*)ws; ws += XSZ;
  float* maskbias     = (float*)ws; ws += (size_t)NB * SEQ * 4;

  wtrans_kernel<<<dim3(12, 12, 5), 256, 0, stream>>>(gWq, gWk, gWv, gWo, WqT, WkT, WvT, WoT,
                                                     gmask, maskbias);

  QKVArgs ga;
  ga.A[0] = gq; ga.A[1] = gk; ga.A[2] = gv;
  ga.BT[0] = WqT; ga.BT[1] = WkT; ga.BT[2] = WvT;
  ga.bias[0] = gbq; ga.bias[1] = gbk; ga.bias[2] = gbv;
  ga.out[0] = Qh; ga.out[1] = Kh; ga.out[2] = Vt;
  ga.scale = 0.18033688011112042f;  // 0.125 * log2(e)
  gemm_qkv_kernel<<<dim3(32, 6, 3), 256, 0, stream>>>(ga);

  flash_kernel<<<dim3(768), 512, 0, stream>>>(Qh, Kh, Vt, maskbias, AO);
  gemm_o_kernel<<<dim3(32, 6), 256, 0, stream>>>(AO, WoT, gbo, out);
}

// Round 4
// 166.782 us; speedup vs baseline: 1.0671x; 1.0671x over previous
//
#include <hip/hip_runtime.h>

#define DMODEL 768
#define NHEAD  12
#define DK     64
#define NB     2
#define SEQ    2048
#define NTOK   (NB*SEQ)     // 4096
#define GKIT   (DMODEL/32)  // 24

using bf16x8 = __attribute__((ext_vector_type(8))) short;
using f32x4  = __attribute__((ext_vector_type(4))) float;

typedef __attribute__((address_space(1))) const unsigned int gas_u32;
typedef __attribute__((address_space(3))) unsigned int las_u32;

__device__ __forceinline__ void gload_lds16(const void* g, void* l) {
  __builtin_amdgcn_global_load_lds((gas_u32*)g, (las_u32*)l, 16, 0, 0);
}

__device__ __forceinline__ unsigned short f2bf(float f) {
  unsigned int u = __builtin_bit_cast(unsigned int, f);
  u = (u + 0x7FFFu + ((u >> 16) & 1u)) >> 16;
  return (unsigned short)u;
}

__device__ __forceinline__ unsigned cvtpk_bf16(float lo, float hi) {
  unsigned r;
  asm volatile("v_cvt_pk_bf16_f32 %0, %1, %2" : "=v"(r) : "v"(lo), "v"(hi));
  return r;
}

// ---------------- f32 -> bf16 convert (query/key/value), 8 elem/thread ----------------
__global__ __launch_bounds__(256) void convx_kernel(
    const float* __restrict__ q, const float* __restrict__ k, const float* __restrict__ v,
    unsigned short* __restrict__ oq, unsigned short* __restrict__ ok, unsigned short* __restrict__ ov) {
  const float* in = blockIdx.z == 0 ? q : (blockIdx.z == 1 ? k : v);
  unsigned short* out = blockIdx.z == 0 ? oq : (blockIdx.z == 1 ? ok : ov);
  size_t i = ((size_t)blockIdx.x * 256 + threadIdx.x) * 8;
  float4 f0 = *(const float4*)(in + i);
  float4 f1 = *(const float4*)(in + i + 4);
  uint4 w;
  w.x = cvtpk_bf16(f0.x, f0.y); w.y = cvtpk_bf16(f0.z, f0.w);
  w.z = cvtpk_bf16(f1.x, f1.y); w.w = cvtpk_bf16(f1.z, f1.w);
  *(uint4*)(out + i) = w;
}

// ---------------- W (f32, [K][N]) -> W^T (bf16, [N][K]) + mask bias ----------------
__global__ __launch_bounds__(256) void wtrans_kernel(
    const float* __restrict__ w0, const float* __restrict__ w1,
    const float* __restrict__ w2, const float* __restrict__ w3,
    unsigned short* __restrict__ o0, unsigned short* __restrict__ o1,
    unsigned short* __restrict__ o2, unsigned short* __restrict__ o3,
    const int* __restrict__ mask, float* __restrict__ maskbias) {
  __shared__ unsigned short tile[64][80];
  int z = blockIdx.z;
  if (z == 4) {
    if (blockIdx.x == 0 && blockIdx.y == 0) {
      for (int i = threadIdx.x; i < NB * SEQ; i += 256)
        maskbias[i] = mask[i] ? 0.f : -1.4426950408889634e9f;  // -1e9 * log2(e)
    }
    return;
  }
  const float* in = z == 0 ? w0 : z == 1 ? w1 : z == 2 ? w2 : w3;
  unsigned short* out = z == 0 ? o0 : z == 1 ? o1 : z == 2 ? o2 : o3;
  int c0 = blockIdx.x * 64, r0 = blockIdx.y * 64;
  int t = threadIdx.x, row = t >> 2, ch = t & 3;
#pragma unroll
  for (int j4 = 0; j4 < 4; ++j4) {
    float4 f = *(const float4*)(in + (size_t)(r0 + row) * DMODEL + c0 + ch * 16 + j4 * 4);
    tile[row][ch * 16 + j4 * 4 + 0] = f2bf(f.x);
    tile[row][ch * 16 + j4 * 4 + 1] = f2bf(f.y);
    tile[row][ch * 16 + j4 * 4 + 2] = f2bf(f.z);
    tile[row][ch * 16 + j4 * 4 + 3] = f2bf(f.w);
  }
  __syncthreads();
  uint4 wA, wB;
  unsigned short* ta = (unsigned short*)&wA;
  unsigned short* tb = (unsigned short*)&wB;
#pragma unroll
  for (int j = 0; j < 8; ++j) { ta[j] = tile[ch * 16 + j][row]; tb[j] = tile[ch * 16 + 8 + j][row]; }
  unsigned short* ob = out + (size_t)(c0 + row) * DMODEL + r0 + ch * 16;
  *(uint4*)ob = wA;
  *(uint4*)(ob + 8) = wB;
}

// ---------------- GEMM core: 128x128 tile, BK=32, async dbuf via global_load_lds ----------------
__device__ __forceinline__ void gemm_stage(const unsigned short* A, const unsigned short* BT,
    unsigned short* As, unsigned short* Bs, int rowbase, int colbase, int kt, int wave, int lane) {
  int rb = wave * 32;
  int r = lane >> 2, c = lane & 3;
#pragma unroll
  for (int iss = 0; iss < 2; ++iss) {
    int row = rb + iss * 16 + r;
    gload_lds16(A + (size_t)(rowbase + row) * DMODEL + kt * 32 + c * 8, As + (rb + iss * 16) * 32);
    gload_lds16(BT + (size_t)(colbase + row) * DMODEL + kt * 32 + c * 8, Bs + (rb + iss * 16) * 32);
  }
}

__device__ __forceinline__ void gemm_core(const unsigned short* A, const unsigned short* BT,
    char* gsm, int rowbase, int colbase, f32x4 acc[4][4]) {
  unsigned short* AsAll = (unsigned short*)gsm;            // [2][4096]
  unsigned short* BsAll = (unsigned short*)(gsm + 16384);  // [2][4096]
  int t = threadIdx.x, lane = t & 63, wave = t >> 6;
  int wr = wave >> 1, wc = wave & 1, l16 = lane & 15, lk = lane >> 4;
  gemm_stage(A, BT, AsAll, BsAll, rowbase, colbase, 0, wave, lane);
  __syncthreads();
  for (int kt = 0; kt < GKIT; ++kt) {
    int cur = kt & 1;
    if (kt < GKIT - 1)
      gemm_stage(A, BT, AsAll + (cur ^ 1) * 4096, BsAll + (cur ^ 1) * 4096,
                 rowbase, colbase, kt + 1, wave, lane);
    unsigned short* As = AsAll + cur * 4096;
    unsigned short* Bs = BsAll + cur * 4096;
    bf16x8 a[4], bb[4];
#pragma unroll
    for (int m = 0; m < 4; ++m) a[m] = *(const bf16x8*)(As + (wr * 64 + m * 16 + l16) * 32 + lk * 8);
#pragma unroll
    for (int n = 0; n < 4; ++n) bb[n] = *(const bf16x8*)(Bs + (wc * 64 + n * 16 + l16) * 32 + lk * 8);
    __builtin_amdgcn_s_setprio(1);
#pragma unroll
    for (int m = 0; m < 4; ++m)
#pragma unroll
      for (int n = 0; n < 4; ++n)
        acc[m][n] = __builtin_amdgcn_mfma_f32_16x16x32_bf16(a[m], bb[n], acc[m][n], 0, 0, 0);
    __builtin_amdgcn_s_setprio(0);
    __syncthreads();
  }
}

struct QKVArgs {
  const unsigned short* A[3];
  const unsigned short* BT[3];
  const float* bias[3];
  unsigned short* out[3];   // Qh, Kh, Vt(transposed)
  float scale;              // for z==0 (Q): 0.125*log2(e)
};

// QKV projections; z=2 writes V transposed [B,H,DK,S]
__global__ __launch_bounds__(256) void gemm_qkv_kernel(QKVArgs ga) {
  __shared__ char gsm[32768];
  int z = blockIdx.z;
  int rowbase = blockIdx.x * 128, colbase = blockIdx.y * 128;
  f32x4 acc[4][4];
#pragma unroll
  for (int m = 0; m < 4; ++m)
#pragma unroll
    for (int n = 0; n < 4; ++n) acc[m][n] = (f32x4){0.f, 0.f, 0.f, 0.f};
  gemm_core(ga.A[z], ga.BT[z], gsm, rowbase, colbase, acc);
  const float* bias = ga.bias[z];
  int t = threadIdx.x, lane = t & 63, wave = t >> 6;
  int wr = wave >> 1, wc = wave & 1, l16 = lane & 15, lk = lane >> 4;
  if (z == 2) {
    // transpose epilogue: acc -> LDS (swizzled) -> coalesced Vt writes
#pragma unroll
    for (int n = 0; n < 4; ++n) {
      int c = wc * 64 + n * 16 + l16;
      float bv = bias[colbase + c];
      int swz = (c & 7) << 4;
#pragma unroll
      for (int m = 0; m < 4; ++m) {
        uint2 w;
        w.x = cvtpk_bf16(acc[m][n][0] + bv, acc[m][n][1] + bv);
        w.y = cvtpk_bf16(acc[m][n][2] + bv, acc[m][n][3] + bv);
        int rp = wr * 64 + m * 16 + lk * 4;
        *(uint2*)(gsm + c * 256 + ((rp * 2) ^ swz)) = w;
      }
    }
    __syncthreads();
    int c = t >> 1, hf = t & 1;
    int swz2 = (c & 7) << 4;
    int gcol = colbase + c;
    int hh = gcol >> 6, dd = gcol & 63;
    int bb2 = rowbase >> 11;
    int s0 = (rowbase & 2047) + hf * 64;
    unsigned short* dst = ga.out[2] + ((size_t)(bb2 * NHEAD + hh) * DK + dd) * SEQ + s0;
#pragma unroll
    for (int j = 0; j < 8; ++j) {
      uint4 w = *(const uint4*)(gsm + c * 256 + ((hf * 128 + j * 16) ^ swz2));
      *(uint4*)(dst + j * 8) = w;
    }
  } else {
    float scale = (z == 0) ? ga.scale : 1.f;
    unsigned short* out = ga.out[z];
#pragma unroll
    for (int n = 0; n < 4; ++n) {
      int gcol = colbase + wc * 64 + n * 16 + l16;
      float bv = bias[gcol];
      int h = gcol >> 6, d = gcol & 63;
#pragma unroll
      for (int m = 0; m < 4; ++m) {
        int growb = rowbase + wr * 64 + m * 16 + lk * 4;
#pragma unroll
        for (int i = 0; i < 4; ++i) {
          int grow = growb + i;
          int b = grow >> 11, s = grow & 2047;
          out[((size_t)(b * NHEAD + h) * SEQ + s) * DK + d] = f2bf((acc[m][n][i] + bv) * scale);
        }
      }
    }
  }
}

// Output projection: out = AO @ Wo + bo, f32 result
__global__ __launch_bounds__(256) void gemm_o_kernel(
    const unsigned short* __restrict__ A, const unsigned short* __restrict__ BT,
    const float* __restrict__ bias, float* __restrict__ out) {
  __shared__ char gsm[32768];
  int rowbase = blockIdx.x * 128, colbase = blockIdx.y * 128;
  f32x4 acc[4][4];
#pragma unroll
  for (int m = 0; m < 4; ++m)
#pragma unroll
    for (int n = 0; n < 4; ++n) acc[m][n] = (f32x4){0.f, 0.f, 0.f, 0.f};
  gemm_core(A, BT, gsm, rowbase, colbase, acc);
  int lane = threadIdx.x & 63, wave = threadIdx.x >> 6;
  int wr = wave >> 1, wc = wave & 1, l16 = lane & 15, lk = lane >> 4;
#pragma unroll
  for (int n = 0; n < 4; ++n) {
    int gcol = colbase + wc * 64 + n * 16 + l16;
    float bv = bias[gcol];
#pragma unroll
    for (int m = 0; m < 4; ++m) {
      int growb = rowbase + wr * 64 + m * 16 + lk * 4;
#pragma unroll
      for (int i = 0; i < 4; ++i)
        out[(size_t)(growb + i) * DMODEL + gcol] = acc[m][n][i] + bv;
    }
  }
}

// ---------------- flash attention: 4 waves, 24KB LDS, optional block KV-split ----------------
// SPLIT=2: grid 1536 (6 blocks/CU exactly), partials to Opart/Mpart/Lpart, merged later.
// SPLIT=1: grid 768, writes AO directly.
template<int SPLIT>
__global__ __launch_bounds__(256, 6) void flash_kernel(
    const unsigned short* __restrict__ Qh, const unsigned short* __restrict__ Kh,
    const unsigned short* __restrict__ Vt, const float* __restrict__ maskbias,
    unsigned short* __restrict__ AO, float* __restrict__ Opart,
    float* __restrict__ Mpart, float* __restrict__ Lpart) {
  __shared__ char smem[24576];   // Ks 8K | Vs 8K | Ps 8K
  char* Ks = smem;
  char* Vs = smem + 8192;

  int orig = blockIdx.x;
  int xcd = orig & 7, idx = orig >> 3;
  int bh, qt, sp;
  if (SPLIT == 2) {              // 192 per xcd = 3 bh x (32 qt x 2 sp)
    bh = xcd * 3 + idx / 64;
    int r = idx & 63;
    qt = r >> 1; sp = r & 1;
  } else {                       // 96 per xcd
    bh = xcd * 3 + (idx >> 5);
    qt = idx & 31; sp = 0;
  }
  int b = bh / NHEAD, h = bh % NHEAD;
  const int NT = 32 / SPLIT;
  int kv0 = sp * (SEQ / 2);

  int t = threadIdx.x, lane = t & 63, wave = t >> 6;
  int l16 = lane & 15, lk = lane >> 4;
  size_t headQ = (size_t)bh * SEQ * DK;
  size_t headV = (size_t)bh * DK * SEQ;
  int qbase = qt * 64 + wave * 16;

  const unsigned short* Kg = Kh + headQ + (size_t)kv0 * DK;
  const unsigned short* Vg = Vt + headV + kv0;
  const float* mb = maskbias + b * SEQ + kv0;
  char* Pw = smem + 16384 + wave * 2048;

  bf16x8 aq0 = *(const bf16x8*)(Qh + headQ + (size_t)(qbase + l16) * DK + lk * 8);
  bf16x8 aq1 = *(const bf16x8*)(Qh + headQ + (size_t)(qbase + l16) * DK + 32 + lk * 8);

  // staging geometry: 256 threads, 64 rows x 8 chunks(16B); each thread 2 chunks
  int srw = t >> 2, c0 = (t & 3) * 2, c1 = c0 + 1;
  int d0 = srw * 128 + ((c0 ^ (srw & 7)) << 4);
  int d1 = srw * 128 + ((c1 ^ (srw & 7)) << 4);
  size_t kOff0 = (size_t)srw * DK + c0 * 8, kOff1 = (size_t)srw * DK + c1 * 8;
  size_t vOff0 = (size_t)srw * SEQ + c0 * 8, vOff1 = (size_t)srw * SEQ + c1 * 8;

  uint4 kA, kB, vA, vB;
#define LDT(kt_) do { \
    kA = *(const uint4*)(Kg + (size_t)(kt_) * 4096 + kOff0); \
    kB = *(const uint4*)(Kg + (size_t)(kt_) * 4096 + kOff1); \
    vA = *(const uint4*)(Vg + (kt_) * 64 + vOff0); \
    vB = *(const uint4*)(Vg + (kt_) * 64 + vOff1); \
  } while (0)
#define STT() do { \
    *(uint4*)(Ks + d0) = kA; *(uint4*)(Ks + d1) = kB; \
    *(uint4*)(Vs + d0) = vA; *(uint4*)(Vs + d1) = vB; \
  } while (0)

  LDT(0); STT();
  __syncthreads();

  float m_i = -1e30f, l_i = 0.f;
  f32x4 o[4];
#pragma unroll
  for (int n = 0; n < 4; ++n) o[n] = (f32x4){0.f, 0.f, 0.f, 0.f};

  for (int kt = 0; kt < NT; ++kt) {
    if (kt + 1 < NT) { LDT(kt + 1); }
    __builtin_amdgcn_sched_barrier(0);   // pin prefetch issue before compute

    // QK^T (swapped): rows = keys, cols = q; maskbias as C-in
    f32x4 sv[4];
    __builtin_amdgcn_s_setprio(1);
#pragma unroll
    for (int n = 0; n < 4; ++n) {
      f32x4 bias = *(const f32x4*)(mb + kt * 64 + n * 16 + lk * 4);
      int key = n * 16 + l16;
      bf16x8 k0 = *(const bf16x8*)(Ks + ((key * 128 + lk * 16) ^ ((key & 7) << 4)));
      bf16x8 k1 = *(const bf16x8*)(Ks + ((key * 128 + 64 + lk * 16) ^ ((key & 7) << 4)));
      f32x4 zz = __builtin_amdgcn_mfma_f32_16x16x32_bf16(k1, aq1, bias, 0, 0, 0);
      sv[n] = __builtin_amdgcn_mfma_f32_16x16x32_bf16(k0, aq0, zz, 0, 0, 0);
    }
    __builtin_amdgcn_s_setprio(0);

    float pmax = -3.0e38f;
#pragma unroll
    for (int n = 0; n < 4; ++n)
#pragma unroll
      for (int i = 0; i < 4; ++i) pmax = fmaxf(pmax, sv[n][i]);
    pmax = fmaxf(pmax, __shfl_xor(pmax, 16));
    pmax = fmaxf(pmax, __shfl_xor(pmax, 32));

    if (__any(pmax > m_i + 8.0f)) {  // defer-max (log2 domain)
      float mnew = fmaxf(m_i, pmax);
      float corr = exp2f(m_i - mnew);
      l_i *= corr; m_i = mnew;
      float cc0 = __shfl(corr, lk * 4 + 0);
      float cc1 = __shfl(corr, lk * 4 + 1);
      float cc2 = __shfl(corr, lk * 4 + 2);
      float cc3 = __shfl(corr, lk * 4 + 3);
#pragma unroll
      for (int t4 = 0; t4 < 4; ++t4) {
        o[t4][0] *= cc0; o[t4][1] *= cc1; o[t4][2] *= cc2; o[t4][3] *= cc3;
      }
    }

    float su = 0.f;
#pragma unroll
    for (int n = 0; n < 4; ++n)
#pragma unroll
      for (int i = 0; i < 4; ++i) { sv[n][i] = exp2f(sv[n][i] - m_i); su += sv[n][i]; }
    su += __shfl_xor(su, 16);
    su += __shfl_xor(su, 32);
    l_i += su;

    // P -> wave-private LDS (swizzled), then A-fragments
#pragma unroll
    for (int n = 0; n < 4; ++n) {
      uint2 w;
      w.x = cvtpk_bf16(sv[n][0], sv[n][1]);
      w.y = cvtpk_bf16(sv[n][2], sv[n][3]);
      int byt = (l16 * 128 + n * 32 + lk * 8) ^ ((l16 & 7) << 4);
      *(uint2*)(Pw + byt) = w;
    }
    bf16x8 ap0 = *(const bf16x8*)(Pw + ((l16 * 128 + lk * 16) ^ ((l16 & 7) << 4)));
    bf16x8 ap1 = *(const bf16x8*)(Pw + ((l16 * 128 + 64 + lk * 16) ^ ((l16 & 7) << 4)));

    __builtin_amdgcn_s_setprio(1);
#pragma unroll
    for (int t4 = 0; t4 < 4; ++t4) {
      int d = t4 * 16 + l16;
      bf16x8 bv0 = *(const bf16x8*)(Vs + ((d * 128 + lk * 16) ^ ((d & 7) << 4)));
      bf16x8 bv1 = *(const bf16x8*)(Vs + ((d * 128 + 64 + lk * 16) ^ ((d & 7) << 4)));
      o[t4] = __builtin_amdgcn_mfma_f32_16x16x32_bf16(ap0, bv0, o[t4], 0, 0, 0);
      o[t4] = __builtin_amdgcn_mfma_f32_16x16x32_bf16(ap1, bv1, o[t4], 0, 0, 0);
    }
    __builtin_amdgcn_s_setprio(0);

    __syncthreads();                    // all waves done reading Ks/Vs
    if (kt + 1 < NT) {
      STT();                            // commit prefetched tile
      __syncthreads();
    }
  }
#undef LDT
#undef STT

  if (SPLIT == 2) {
    size_t pb = ((size_t)(bh * 32 + qt) * 2 + sp) * 4096;
#pragma unroll
    for (int t4 = 0; t4 < 4; ++t4)
#pragma unroll
      for (int i = 0; i < 4; ++i)
        Opart[pb + (size_t)(wave * 16 + lk * 4 + i) * 64 + t4 * 16 + l16] = o[t4][i];
    if (lk == 0) {
      int qi = ((bh * 32 + qt) * 2 + sp) * 64 + wave * 16 + l16;
      Mpart[qi] = m_i;
      Lpart[qi] = l_i;
    }
  } else {
    float linv = 1.0f / l_i;
    float li_r[4];
#pragma unroll
    for (int i = 0; i < 4; ++i) li_r[i] = __shfl(linv, lk * 4 + i);
#pragma unroll
    for (int t4 = 0; t4 < 4; ++t4) {
      int col = h * DK + t4 * 16 + l16;
#pragma unroll
      for (int i = 0; i < 4; ++i) {
        int srq = qbase + lk * 4 + i;
        AO[(size_t)(b * SEQ + srq) * DMODEL + col] = f2bf(o[t4][i] * li_r[i]);
      }
    }
  }
}

// ---------------- merge the two KV-split halves ----------------
__global__ __launch_bounds__(256) void merge_kernel(
    const float* __restrict__ Opart, const float* __restrict__ Mpart,
    const float* __restrict__ Lpart, unsigned short* __restrict__ AO) {
  int blk = blockIdx.x;          // bh*32 + qt
  int bh = blk >> 5, qt = blk & 31;
  int b = bh / NHEAD, h = bh % NHEAD;
  int t = threadIdx.x;
  int q = t >> 2, dc = (t & 3) * 16;
  size_t base = (size_t)blk * 2 * 4096;
  const float* o0 = Opart + base + (size_t)q * 64 + dc;
  const float* o1 = o0 + 4096;
  int qi = blk * 128 + q;
  float m0 = Mpart[qi], m1 = Mpart[qi + 64];
  float l0 = Lpart[qi], l1 = Lpart[qi + 64];
  float mst = fmaxf(m0, m1);
  float f0 = exp2f(m0 - mst), f1 = exp2f(m1 - mst);
  float linv = 1.f / (l0 * f0 + l1 * f1);
  f0 *= linv; f1 *= linv;
  unsigned short* dst = AO + ((size_t)(b * SEQ + qt * 64 + q)) * DMODEL + h * DK + dc;
#pragma unroll
  for (int j = 0; j < 4; ++j) {
    float4 a = *(const float4*)(o0 + j * 4);
    float4 c = *(const float4*)(o1 + j * 4);
    uint2 w;
    w.x = cvtpk_bf16(a.x * f0 + c.x * f1, a.y * f0 + c.y * f1);
    w.y = cvtpk_bf16(a.z * f0 + c.z * f1, a.w * f0 + c.w * f1);
    *(uint2*)(dst + j * 4) = w;
  }
}

extern "C" void kernel_launch(void* const* d_in, const int* in_sizes, int n_in,
                              void* d_out, int out_size, void* d_ws, size_t ws_size,
                              hipStream_t stream) {
  const float* gq  = (const float*)d_in[0];
  const float* gk  = (const float*)d_in[1];
  const float* gv  = (const float*)d_in[2];
  const int* gmask = (const int*)d_in[3];
  const float* gWq = (const float*)d_in[4];
  const float* gbq = (const float*)d_in[5];
  const float* gWk = (const float*)d_in[6];
  const float* gbk = (const float*)d_in[7];
  const float* gWv = (const float*)d_in[8];
  const float* gbv = (const float*)d_in[9];
  const float* gWo = (const float*)d_in[10];
  const float* gbo = (const float*)d_in[11];
  float* out = (float*)d_out;

  char* ws = (char*)d_ws;
  const size_t XSZ = (size_t)NTOK * DMODEL * 2;   // 6,291,456
  const size_t WSZ = (size_t)DMODEL * DMODEL * 2; // 1,179,648
  const size_t OPSZ = (size_t)768 * 2 * 4096 * 4; // 25,165,824

  // Region A: Opart (flash->merge) aliases Xq/Xk/Xv (convx->gemm_qkv)
  float* Opart = (float*)ws;
  unsigned short* Xq = (unsigned short*)ws;
  unsigned short* Xk = Xq + XSZ / 2;
  unsigned short* Xv = Xk + XSZ / 2;
  char* p = ws + OPSZ;
  float* Mpart = (float*)p; p += (size_t)768 * 128 * 4;
  float* Lpart = (float*)p; p += (size_t)768 * 128 * 4;
  unsigned short* WqT = (unsigned short*)p; p += WSZ;
  unsigned short* WkT = (unsigned short*)p; p += WSZ;
  unsigned short* WvT = (unsigned short*)p; p += WSZ;
  unsigned short* WoT = (unsigned short*)p; p += WSZ;
  unsigned short* Qh  = (unsigned short*)p; p += XSZ;
  unsigned short* Kh  = (unsigned short*)p; p += XSZ;
  unsigned short* Vt  = (unsigned short*)p; p += XSZ;
  unsigned short* AO  = (unsigned short*)p; p += XSZ;
  float* maskbias     = (float*)p; p += (size_t)NB * SEQ * 4;
  size_t needed = (size_t)(p - ws);
  bool split2 = ws_size >= needed;

  convx_kernel<<<dim3(NTOK * DMODEL / 2048, 1, 3), 256, 0, stream>>>(gq, gk, gv, Xq, Xk, Xv);
  wtrans_kernel<<<dim3(12, 12, 5), 256, 0, stream>>>(gWq, gWk, gWv, gWo, WqT, WkT, WvT, WoT,
                                                     gmask, maskbias);

  QKVArgs ga;
  ga.A[0] = Xq; ga.A[1] = Xk; ga.A[2] = Xv;
  ga.BT[0] = WqT; ga.BT[1] = WkT; ga.BT[2] = WvT;
  ga.bias[0] = gbq; ga.bias[1] = gbk; ga.bias[2] = gbv;
  ga.out[0] = Qh; ga.out[1] = Kh; ga.out[2] = Vt;
  ga.scale = 0.18033688011112042f;  // 0.125 * log2(e)
  gemm_qkv_kernel<<<dim3(32, 6, 3), 256, 0, stream>>>(ga);

  if (split2) {
    flash_kernel<2><<<dim3(1536), 256, 0, stream>>>(Qh, Kh, Vt, maskbias, AO, Opart, Mpart, Lpart);
    merge_kernel<<<dim3(768), 256, 0, stream>>>(Opart, Mpart, Lpart, AO);
  } else {
    flash_kernel<1><<<dim3(768), 256, 0, stream>>>(Qh, Kh, Vt, maskbias, AO, Opart, Mpart, Lpart);
  }
  gemm_o_kernel<<<dim3(32, 6), 256, 0, stream>>>(AO, WoT, gbo, out);
}

// Round 5
// 136.363 us; speedup vs baseline: 1.3052x; 1.2231x over previous
//
#include <hip/hip_runtime.h>

#define DMODEL 768
#define NHEAD  12
#define DK     64
#define NB     2
#define SEQ    2048
#define NTOK   (NB*SEQ)     // 4096
#define GKIT   (DMODEL/32)  // 24

using bf16x8 = __attribute__((ext_vector_type(8))) short;
using f32x4  = __attribute__((ext_vector_type(4))) float;

typedef __attribute__((address_space(1))) const unsigned int gas_u32;
typedef __attribute__((address_space(3))) unsigned int las_u32;

__device__ __forceinline__ void gload_lds16(const void* g, void* l) {
  __builtin_amdgcn_global_load_lds((gas_u32*)g, (las_u32*)l, 16, 0, 0);
}

__device__ __forceinline__ unsigned short f2bf(float f) {
  unsigned int u = __builtin_bit_cast(unsigned int, f);
  u = (u + 0x7FFFu + ((u >> 16) & 1u)) >> 16;
  return (unsigned short)u;
}

__device__ __forceinline__ unsigned cvtpk_bf16(float lo, float hi) {
  unsigned r;
  asm volatile("v_cvt_pk_bf16_f32 %0, %1, %2" : "=v"(r) : "v"(lo), "v"(hi));
  return r;
}

// ---------------- f32 -> bf16 convert (query/key/value), 8 elem/thread ----------------
__global__ __launch_bounds__(256) void convx_kernel(
    const float* __restrict__ q, const float* __restrict__ k, const float* __restrict__ v,
    unsigned short* __restrict__ oq, unsigned short* __restrict__ ok, unsigned short* __restrict__ ov) {
  const float* in = blockIdx.z == 0 ? q : (blockIdx.z == 1 ? k : v);
  unsigned short* out = blockIdx.z == 0 ? oq : (blockIdx.z == 1 ? ok : ov);
  size_t i = ((size_t)blockIdx.x * 256 + threadIdx.x) * 8;
  float4 f0 = *(const float4*)(in + i);
  float4 f1 = *(const float4*)(in + i + 4);
  uint4 w;
  w.x = cvtpk_bf16(f0.x, f0.y); w.y = cvtpk_bf16(f0.z, f0.w);
  w.z = cvtpk_bf16(f1.x, f1.y); w.w = cvtpk_bf16(f1.z, f1.w);
  *(uint4*)(out + i) = w;
}

// ---------------- W (f32, [K][N]) -> W^T (bf16, [N][K]) + mask bias ----------------
__global__ __launch_bounds__(256) void wtrans_kernel(
    const float* __restrict__ w0, const float* __restrict__ w1,
    const float* __restrict__ w2, const float* __restrict__ w3,
    unsigned short* __restrict__ o0, unsigned short* __restrict__ o1,
    unsigned short* __restrict__ o2, unsigned short* __restrict__ o3,
    const int* __restrict__ mask, float* __restrict__ maskbias) {
  __shared__ unsigned short tile[64][80];
  int z = blockIdx.z;
  if (z == 4) {
    if (blockIdx.x == 0 && blockIdx.y == 0) {
      for (int i = threadIdx.x; i < NB * SEQ; i += 256)
        maskbias[i] = mask[i] ? 0.f : -1.4426950408889634e9f;  // -1e9 * log2(e)
    }
    return;
  }
  const float* in = z == 0 ? w0 : z == 1 ? w1 : z == 2 ? w2 : w3;
  unsigned short* out = z == 0 ? o0 : z == 1 ? o1 : z == 2 ? o2 : o3;
  int c0 = blockIdx.x * 64, r0 = blockIdx.y * 64;
  int t = threadIdx.x, row = t >> 2, ch = t & 3;
#pragma unroll
  for (int j4 = 0; j4 < 4; ++j4) {
    float4 f = *(const float4*)(in + (size_t)(r0 + row) * DMODEL + c0 + ch * 16 + j4 * 4);
    tile[row][ch * 16 + j4 * 4 + 0] = f2bf(f.x);
    tile[row][ch * 16 + j4 * 4 + 1] = f2bf(f.y);
    tile[row][ch * 16 + j4 * 4 + 2] = f2bf(f.z);
    tile[row][ch * 16 + j4 * 4 + 3] = f2bf(f.w);
  }
  __syncthreads();
  uint4 wA, wB;
  unsigned short* ta = (unsigned short*)&wA;
  unsigned short* tb = (unsigned short*)&wB;
#pragma unroll
  for (int j = 0; j < 8; ++j) { ta[j] = tile[ch * 16 + j][row]; tb[j] = tile[ch * 16 + 8 + j][row]; }
  unsigned short* ob = out + (size_t)(c0 + row) * DMODEL + r0 + ch * 16;
  *(uint4*)ob = wA;
  *(uint4*)(ob + 8) = wB;
}

// ---------------- GEMM core: 128x128 tile, BK=32, async dbuf via global_load_lds ----------------
__device__ __forceinline__ void gemm_stage(const unsigned short* A, const unsigned short* BT,
    unsigned short* As, unsigned short* Bs, int rowbase, int colbase, int kt, int wave, int lane) {
  int rb = wave * 32;
  int r = lane >> 2, c = lane & 3;
#pragma unroll
  for (int iss = 0; iss < 2; ++iss) {
    int row = rb + iss * 16 + r;
    gload_lds16(A + (size_t)(rowbase + row) * DMODEL + kt * 32 + c * 8, As + (rb + iss * 16) * 32);
    gload_lds16(BT + (size_t)(colbase + row) * DMODEL + kt * 32 + c * 8, Bs + (rb + iss * 16) * 32);
  }
}

__device__ __forceinline__ void gemm_core(const unsigned short* A, const unsigned short* BT,
    char* gsm, int rowbase, int colbase, f32x4 acc[4][4]) {
  unsigned short* AsAll = (unsigned short*)gsm;            // [2][4096]
  unsigned short* BsAll = (unsigned short*)(gsm + 16384);  // [2][4096]
  int t = threadIdx.x, lane = t & 63, wave = t >> 6;
  int wr = wave >> 1, wc = wave & 1, l16 = lane & 15, lk = lane >> 4;
  gemm_stage(A, BT, AsAll, BsAll, rowbase, colbase, 0, wave, lane);
  __syncthreads();
  for (int kt = 0; kt < GKIT; ++kt) {
    int cur = kt & 1;
    if (kt < GKIT - 1)
      gemm_stage(A, BT, AsAll + (cur ^ 1) * 4096, BsAll + (cur ^ 1) * 4096,
                 rowbase, colbase, kt + 1, wave, lane);
    unsigned short* As = AsAll + cur * 4096;
    unsigned short* Bs = BsAll + cur * 4096;
    bf16x8 a[4], bb[4];
#pragma unroll
    for (int m = 0; m < 4; ++m) a[m] = *(const bf16x8*)(As + (wr * 64 + m * 16 + l16) * 32 + lk * 8);
#pragma unroll
    for (int n = 0; n < 4; ++n) bb[n] = *(const bf16x8*)(Bs + (wc * 64 + n * 16 + l16) * 32 + lk * 8);
    __builtin_amdgcn_s_setprio(1);
#pragma unroll
    for (int m = 0; m < 4; ++m)
#pragma unroll
      for (int n = 0; n < 4; ++n)
        acc[m][n] = __builtin_amdgcn_mfma_f32_16x16x32_bf16(a[m], bb[n], acc[m][n], 0, 0, 0);
    __builtin_amdgcn_s_setprio(0);
    __syncthreads();
  }
}

struct QKVArgs {
  const unsigned short* A[3];
  const unsigned short* BT[3];
  const float* bias[3];
  unsigned short* out[3];   // Qh, Kh, Vt(transposed)
  float scale;              // for z==0 (Q): 0.125*log2(e)
};

// QKV projections; z=2 writes V transposed [B,H,DK,S]
__global__ __launch_bounds__(256) void gemm_qkv_kernel(QKVArgs ga) {
  __shared__ char gsm[32768];
  int z = blockIdx.z;
  int rowbase = blockIdx.x * 128, colbase = blockIdx.y * 128;
  f32x4 acc[4][4];
#pragma unroll
  for (int m = 0; m < 4; ++m)
#pragma unroll
    for (int n = 0; n < 4; ++n) acc[m][n] = (f32x4){0.f, 0.f, 0.f, 0.f};
  gemm_core(ga.A[z], ga.BT[z], gsm, rowbase, colbase, acc);
  const float* bias = ga.bias[z];
  int t = threadIdx.x, lane = t & 63, wave = t >> 6;
  int wr = wave >> 1, wc = wave & 1, l16 = lane & 15, lk = lane >> 4;
  if (z == 2) {
    // transpose epilogue: acc -> LDS (swizzled) -> coalesced Vt writes
#pragma unroll
    for (int n = 0; n < 4; ++n) {
      int c = wc * 64 + n * 16 + l16;
      float bv = bias[colbase + c];
      int swz = (c & 7) << 4;
#pragma unroll
      for (int m = 0; m < 4; ++m) {
        uint2 w;
        w.x = cvtpk_bf16(acc[m][n][0] + bv, acc[m][n][1] + bv);
        w.y = cvtpk_bf16(acc[m][n][2] + bv, acc[m][n][3] + bv);
        int rp = wr * 64 + m * 16 + lk * 4;
        *(uint2*)(gsm + c * 256 + ((rp * 2) ^ swz)) = w;
      }
    }
    __syncthreads();
    int c = t >> 1, hf = t & 1;
    int swz2 = (c & 7) << 4;
    int gcol = colbase + c;
    int hh = gcol >> 6, dd = gcol & 63;
    int bb2 = rowbase >> 11;
    int s0 = (rowbase & 2047) + hf * 64;
    unsigned short* dst = ga.out[2] + ((size_t)(bb2 * NHEAD + hh) * DK + dd) * SEQ + s0;
#pragma unroll
    for (int j = 0; j < 8; ++j) {
      uint4 w = *(const uint4*)(gsm + c * 256 + ((hf * 128 + j * 16) ^ swz2));
      *(uint4*)(dst + j * 8) = w;
    }
  } else {
    float scale = (z == 0) ? ga.scale : 1.f;
    unsigned short* out = ga.out[z];
#pragma unroll
    for (int n = 0; n < 4; ++n) {
      int gcol = colbase + wc * 64 + n * 16 + l16;
      float bv = bias[gcol];
      int h = gcol >> 6, d = gcol & 63;
#pragma unroll
      for (int m = 0; m < 4; ++m) {
        int growb = rowbase + wr * 64 + m * 16 + lk * 4;
#pragma unroll
        for (int i = 0; i < 4; ++i) {
          int grow = growb + i;
          int b = grow >> 11, s = grow & 2047;
          out[((size_t)(b * NHEAD + h) * SEQ + s) * DK + d] = f2bf((acc[m][n][i] + bv) * scale);
        }
      }
    }
  }
}

// Output projection: out = AO @ Wo + bo, f32 result
__global__ __launch_bounds__(256) void gemm_o_kernel(
    const unsigned short* __restrict__ A, const unsigned short* __restrict__ BT,
    const float* __restrict__ bias, float* __restrict__ out) {
  __shared__ char gsm[32768];
  int rowbase = blockIdx.x * 128, colbase = blockIdx.y * 128;
  f32x4 acc[4][4];
#pragma unroll
  for (int m = 0; m < 4; ++m)
#pragma unroll
    for (int n = 0; n < 4; ++n) acc[m][n] = (f32x4){0.f, 0.f, 0.f, 0.f};
  gemm_core(A, BT, gsm, rowbase, colbase, acc);
  int lane = threadIdx.x & 63, wave = threadIdx.x >> 6;
  int wr = wave >> 1, wc = wave & 1, l16 = lane & 15, lk = lane >> 4;
#pragma unroll
  for (int n = 0; n < 4; ++n) {
    int gcol = colbase + wc * 64 + n * 16 + l16;
    float bv = bias[gcol];
#pragma unroll
    for (int m = 0; m < 4; ++m) {
      int growb = rowbase + wr * 64 + m * 16 + lk * 4;
#pragma unroll
      for (int i = 0; i < 4; ++i)
        out[(size_t)(growb + i) * DMODEL + gcol] = acc[m][n][i] + bv;
    }
  }
}

// ---------------- flash attention: 8 waves, 128 q-rows/block, dbuf gload_lds ----------------
// SPLIT=2: grid 768 (3 blocks/CU, 24 waves/CU), halves of KV; merged by merge_kernel.
// SPLIT=1: grid 384, full KV, writes AO directly.
template<int SPLIT>
__global__ __launch_bounds__(512, 6) void flash_kernel(
    const unsigned short* __restrict__ Qh, const unsigned short* __restrict__ Kh,
    const unsigned short* __restrict__ Vt, const float* __restrict__ maskbias,
    unsigned short* __restrict__ AO, float* __restrict__ Opart,
    float* __restrict__ Mpart, float* __restrict__ Lpart) {
  __shared__ char smem[49152];   // Ks dbuf 16K | Vs dbuf 16K | Ps 16K
  char* Ks = smem;
  char* Vs = smem + 16384;

  int orig = blockIdx.x;
  int xcd = orig & 7, idx = orig >> 3;
  int bh, qt, sp;
  if (SPLIT == 2) {              // 96/xcd = 3 bh x (16 qt x 2 sp)
    bh = xcd * 3 + idx / 32;
    int r = idx & 31; qt = r >> 1; sp = r & 1;
  } else {                       // 48/xcd = 3 bh x 16 qt
    bh = xcd * 3 + idx / 16;
    qt = idx & 15; sp = 0;
  }
  int b = bh / NHEAD, h = bh % NHEAD;
  const int NT = 32 / SPLIT;
  int kv0 = sp * (SEQ / SPLIT);

  int t = threadIdx.x, lane = t & 63, wave = t >> 6;
  int l16 = lane & 15, lk = lane >> 4;
  size_t headQ = (size_t)bh * SEQ * DK;
  size_t headV = (size_t)bh * DK * SEQ;
  int qbase = qt * 128 + wave * 16;

  const unsigned short* Kg = Kh + headQ + (size_t)kv0 * DK;
  const unsigned short* Vg = Vt + headV + kv0;
  const float* mb = maskbias + b * SEQ + kv0;
  char* Pw = smem + 32768 + wave * 2048;

  bf16x8 aq0 = *(const bf16x8*)(Qh + headQ + (size_t)(qbase + l16) * DK + lk * 8);
  bf16x8 aq1 = *(const bf16x8*)(Qh + headQ + (size_t)(qbase + l16) * DK + 32 + lk * 8);

  // staging: 512 threads cover 64 rows x 8 chunks(16B); 1 K-load + 1 V-load each.
  // LDS dest is linear per wave (base + lane*16); swizzle applied on global source.
  int srw = t >> 3, sc = t & 7;
  size_t kOff = (size_t)srw * DK + ((sc ^ (srw & 7)) << 3);
  size_t vOff = (size_t)srw * SEQ + ((sc ^ (srw & 7)) << 3);
  char* kDst = Ks + wave * 1024;
  char* vDst = Vs + wave * 1024;

  gload_lds16(Kg + kOff, kDst);
  gload_lds16(Vg + vOff, vDst);
  __syncthreads();

  float m_i = -1e30f, l_i = 0.f;
  f32x4 o[4];
#pragma unroll
  for (int n = 0; n < 4; ++n) o[n] = (f32x4){0.f, 0.f, 0.f, 0.f};

  for (int kt = 0; kt < NT; ++kt) {
    int cur = kt & 1;
    if (kt + 1 < NT) {   // async prefetch next tile into other buffer
      gload_lds16(Kg + (size_t)(kt + 1) * 4096 + kOff, kDst + (cur ^ 1) * 8192);
      gload_lds16(Vg + (kt + 1) * 64 + vOff, vDst + (cur ^ 1) * 8192);
    }
    const char* kb = Ks + cur * 8192;
    const char* vb = Vs + cur * 8192;

    // QK^T (swapped): rows = keys, cols = q; maskbias as C-in
    f32x4 sv[4];
    __builtin_amdgcn_s_setprio(1);
#pragma unroll
    for (int n = 0; n < 4; ++n) {
      f32x4 bias = *(const f32x4*)(mb + kt * 64 + n * 16 + lk * 4);
      int key = n * 16 + l16;
      bf16x8 k0 = *(const bf16x8*)(kb + ((key * 128 + lk * 16) ^ ((key & 7) << 4)));
      bf16x8 k1 = *(const bf16x8*)(kb + ((key * 128 + 64 + lk * 16) ^ ((key & 7) << 4)));
      f32x4 zz = __builtin_amdgcn_mfma_f32_16x16x32_bf16(k1, aq1, bias, 0, 0, 0);
      sv[n] = __builtin_amdgcn_mfma_f32_16x16x32_bf16(k0, aq0, zz, 0, 0, 0);
    }
    __builtin_amdgcn_s_setprio(0);

    float pmax = -3.0e38f;
#pragma unroll
    for (int n = 0; n < 4; ++n)
#pragma unroll
      for (int i = 0; i < 4; ++i) pmax = fmaxf(pmax, sv[n][i]);
    pmax = fmaxf(pmax, __shfl_xor(pmax, 16));
    pmax = fmaxf(pmax, __shfl_xor(pmax, 32));

    if (__any(pmax > m_i + 8.0f)) {  // defer-max (log2 domain)
      float mnew = fmaxf(m_i, pmax);
      float corr = exp2f(m_i - mnew);
      l_i *= corr; m_i = mnew;
      float cc0 = __shfl(corr, lk * 4 + 0);
      float cc1 = __shfl(corr, lk * 4 + 1);
      float cc2 = __shfl(corr, lk * 4 + 2);
      float cc3 = __shfl(corr, lk * 4 + 3);
#pragma unroll
      for (int t4 = 0; t4 < 4; ++t4) {
        o[t4][0] *= cc0; o[t4][1] *= cc1; o[t4][2] *= cc2; o[t4][3] *= cc3;
      }
    }

    float su = 0.f;
#pragma unroll
    for (int n = 0; n < 4; ++n)
#pragma unroll
      for (int i = 0; i < 4; ++i) { sv[n][i] = exp2f(sv[n][i] - m_i); su += sv[n][i]; }
    su += __shfl_xor(su, 16);
    su += __shfl_xor(su, 32);
    l_i += su;

    // P -> wave-private LDS (swizzled), then A-fragments
#pragma unroll
    for (int n = 0; n < 4; ++n) {
      uint2 w;
      w.x = cvtpk_bf16(sv[n][0], sv[n][1]);
      w.y = cvtpk_bf16(sv[n][2], sv[n][3]);
      int byt = (l16 * 128 + n * 32 + lk * 8) ^ ((l16 & 7) << 4);
      *(uint2*)(Pw + byt) = w;
    }
    bf16x8 ap0 = *(const bf16x8*)(Pw + ((l16 * 128 + lk * 16) ^ ((l16 & 7) << 4)));
    bf16x8 ap1 = *(const bf16x8*)(Pw + ((l16 * 128 + 64 + lk * 16) ^ ((l16 & 7) << 4)));

    __builtin_amdgcn_s_setprio(1);
#pragma unroll
    for (int t4 = 0; t4 < 4; ++t4) {
      int d = t4 * 16 + l16;
      bf16x8 bv0 = *(const bf16x8*)(vb + ((d * 128 + lk * 16) ^ ((d & 7) << 4)));
      bf16x8 bv1 = *(const bf16x8*)(vb + ((d * 128 + 64 + lk * 16) ^ ((d & 7) << 4)));
      o[t4] = __builtin_amdgcn_mfma_f32_16x16x32_bf16(ap0, bv0, o[t4], 0, 0, 0);
      o[t4] = __builtin_amdgcn_mfma_f32_16x16x32_bf16(ap1, bv1, o[t4], 0, 0, 0);
    }
    __builtin_amdgcn_s_setprio(0);
    __syncthreads();   // all waves done with buf[cur]; prefetch drained here
  }

  if (SPLIT == 2) {
    size_t pb = ((size_t)(bh * 16 + qt) * 2 + sp) * (128 * 64);
#pragma unroll
    for (int t4 = 0; t4 < 4; ++t4)
#pragma unroll
      for (int i = 0; i < 4; ++i)
        Opart[pb + (size_t)(wave * 16 + lk * 4 + i) * 64 + t4 * 16 + l16] = o[t4][i];
    if (lk == 0) {
      int qi = ((bh * 16 + qt) * 2 + sp) * 128 + wave * 16 + l16;
      Mpart[qi] = m_i;
      Lpart[qi] = l_i;
    }
  } else {
    float linv = 1.0f / l_i;
    float li_r[4];
#pragma unroll
    for (int i = 0; i < 4; ++i) li_r[i] = __shfl(linv, lk * 4 + i);
#pragma unroll
    for (int t4 = 0; t4 < 4; ++t4) {
      int col = h * DK + t4 * 16 + l16;
#pragma unroll
      for (int i = 0; i < 4; ++i) {
        int srq = qbase + lk * 4 + i;
        AO[(size_t)(b * SEQ + srq) * DMODEL + col] = f2bf(o[t4][i] * li_r[i]);
      }
    }
  }
}

// ---------------- merge the two KV-split halves ----------------
__global__ __launch_bounds__(256) void merge_kernel(
    const float* __restrict__ Opart, const float* __restrict__ Mpart,
    const float* __restrict__ Lpart, unsigned short* __restrict__ AO) {
  int blk = blockIdx.x;            // [0,768): bh(24) x qt(16) x qhalf(2)
  int qh = blk & 1;
  int qt = (blk >> 1) & 15;
  int bh = blk >> 5;
  int b = bh / NHEAD, h = bh % NHEAD;
  int t = threadIdx.x;
  int q = t >> 2, dc = (t & 3) * 16;       // q in [0,64), 16 d-cols/thread
  size_t base0 = ((size_t)(bh * 16 + qt) * 2) * 8192 + (size_t)(qh * 64 + q) * 64 + dc;
  const float* o0 = Opart + base0;
  const float* o1 = o0 + 8192;
  int qi = (bh * 16 + qt) * 2 * 128 + qh * 64 + q;
  float m0 = Mpart[qi], m1 = Mpart[qi + 128];
  float l0 = Lpart[qi], l1 = Lpart[qi + 128];
  float mst = fmaxf(m0, m1);
  float f0 = exp2f(m0 - mst), f1 = exp2f(m1 - mst);
  float linv = 1.f / (l0 * f0 + l1 * f1);
  f0 *= linv; f1 *= linv;
  int row = qt * 128 + qh * 64 + q;
  unsigned short* dst = AO + ((size_t)(b * SEQ + row)) * DMODEL + h * DK + dc;
#pragma unroll
  for (int j = 0; j < 4; ++j) {
    float4 a = *(const float4*)(o0 + j * 4);
    float4 c = *(const float4*)(o1 + j * 4);
    uint2 w;
    w.x = cvtpk_bf16(a.x * f0 + c.x * f1, a.y * f0 + c.y * f1);
    w.y = cvtpk_bf16(a.z * f0 + c.z * f1, a.w * f0 + c.w * f1);
    *(uint2*)(dst + j * 4) = w;
  }
}

extern "C" void kernel_launch(void* const* d_in, const int* in_sizes, int n_in,
                              void* d_out, int out_size, void* d_ws, size_t ws_size,
                              hipStream_t stream) {
  const float* gq  = (const float*)d_in[0];
  const float* gk  = (const float*)d_in[1];
  const float* gv  = (const float*)d_in[2];
  const int* gmask = (const int*)d_in[3];
  const float* gWq = (const float*)d_in[4];
  const float* gbq = (const float*)d_in[5];
  const float* gWk = (const float*)d_in[6];
  const float* gbk = (const float*)d_in[7];
  const float* gWv = (const float*)d_in[8];
  const float* gbv = (const float*)d_in[9];
  const float* gWo = (const float*)d_in[10];
  const float* gbo = (const float*)d_in[11];
  float* out = (float*)d_out;

  char* ws = (char*)d_ws;
  const size_t XSZ = (size_t)NTOK * DMODEL * 2;   // 6,291,456
  const size_t WSZ = (size_t)DMODEL * DMODEL * 2; // 1,179,648
  const size_t OPSZ = (size_t)768 * 8192 * 4;     // 25,165,824 (24*16*2 parts x 128q x 64d f32)

  // Region A: Opart (flash->merge) aliases Xq/Xk/Xv (convx->gemm_qkv)
  float* Opart = (float*)ws;
  unsigned short* Xq = (unsigned short*)ws;
  unsigned short* Xk = Xq + XSZ / 2;
  unsigned short* Xv = Xk + XSZ / 2;
  char* p = ws + OPSZ;
  float* Mpart = (float*)p; p += (size_t)768 * 128 * 4;
  float* Lpart = (float*)p; p += (size_t)768 * 128 * 4;
  unsigned short* WqT = (unsigned short*)p; p += WSZ;
  unsigned short* WkT = (unsigned short*)p; p += WSZ;
  unsigned short* WvT = (unsigned short*)p; p += WSZ;
  unsigned short* WoT = (unsigned short*)p; p += WSZ;
  unsigned short* Qh  = (unsigned short*)p; p += XSZ;
  unsigned short* Kh  = (unsigned short*)p; p += XSZ;
  unsigned short* Vt  = (unsigned short*)p; p += XSZ;
  unsigned short* AO  = (unsigned short*)p; p += XSZ;
  float* maskbias     = (float*)p; p += (size_t)NB * SEQ * 4;
  size_t needed = (size_t)(p - ws);
  bool split2 = ws_size >= needed;

  convx_kernel<<<dim3(NTOK * DMODEL / 2048, 1, 3), 256, 0, stream>>>(gq, gk, gv, Xq, Xk, Xv);
  wtrans_kernel<<<dim3(12, 12, 5), 256, 0, stream>>>(gWq, gWk, gWv, gWo, WqT, WkT, WvT, WoT,
                                                     gmask, maskbias);

  QKVArgs ga;
  ga.A[0] = Xq; ga.A[1] = Xk; ga.A[2] = Xv;
  ga.BT[0] = WqT; ga.BT[1] = WkT; ga.BT[2] = WvT;
  ga.bias[0] = gbq; ga.bias[1] = gbk; ga.bias[2] = gbv;
  ga.out[0] = Qh; ga.out[1] = Kh; ga.out[2] = Vt;
  ga.scale = 0.18033688011112042f;  // 0.125 * log2(e)
  gemm_qkv_kernel<<<dim3(32, 6, 3), 256, 0, stream>>>(ga);

  if (split2) {
    flash_kernel<2><<<dim3(768), 512, 0, stream>>>(Qh, Kh, Vt, maskbias, AO, Opart, Mpart, Lpart);
    merge_kernel<<<dim3(768), 256, 0, stream>>>(Opart, Mpart, Lpart, AO);
  } else {
    flash_kernel<1><<<dim3(384), 512, 0, stream>>>(Qh, Kh, Vt, maskbias, AO, Opart, Mpart, Lpart);
  }
  gemm_o_kernel<<<dim3(32, 6), 256, 0, stream>>>(AO, WoT, gbo, out);
}